// Round 10
// baseline (3226.373 us; speedup 1.0000x reference)
//
#include <hip/hip_runtime.h>
#include <cstdint>
#include <cstddef>

#define B_    64
#define NP1   1025
#define N_    1024
#define D_    256
#define DP1   257
#define L_    4
#define H_    4
#define MT    1024   // ZbT row length (m dim); m=1024 (masked key) excluded
#define NCHE  32     // 32 chunks x 32 m = 1024
#define IPAD  272
#define TR_   1024   // T rows per (b,h): n=0..1023 (row 1024 handled in-kernel tail)

typedef __bf16 bf16;
typedef bf16 bf16x4 __attribute__((ext_vector_type(4)));
typedef bf16 bf16x8 __attribute__((ext_vector_type(8)));
typedef float f32x4 __attribute__((ext_vector_type(4)));

__device__ __forceinline__ f32x4 mfma16(bf16x8 a, bf16x8 b, f32x4 c) {
    return __builtin_amdgcn_mfma_f32_16x16x32_bf16(a, b, c, 0, 0, 0);
}

__device__ __forceinline__ void async16(const void* g, void* l) {
    __builtin_amdgcn_global_load_lds(
        (const __attribute__((address_space(1))) void*)g,
        (__attribute__((address_space(3))) void*)l, 16, 0, 0);
}

// ---------------------------------------------------------------------------
__global__ void k_prep_pq(const float* __restrict__ ap,
                          bf16* __restrict__ Pb, bf16* __restrict__ Qt) {
    int idx = blockIdx.x * 256 + threadIdx.x;   // L*H*D*D = 1048576
    int j  = idx & 255;
    int i  = (idx >> 8) & 255;
    int lh = idx >> 16;
    const float* base = ap + (size_t)lh * 2 * D_ * D_;
    float p = base[i * D_ + j];
    float q = base[D_ * D_ + i * D_ + j];
    Pb[((size_t)lh * D_ + i) * D_ + j] = (bf16)p;
    Qt[((size_t)lh * D_ + j) * D_ + i] = (bf16)q;   // Qt[j][i] = Q[i][j]
}

// ---------------------------------------------------------------------------
// Per-layer staging: Zb[b][m][j] (j<256) and ZbT[b][j][m] (j<257), m<1024.
// Runs after each fused k_attn completes Z(l+1); doubles as the L2 warm-up
// for the next k_attn's staging.
// ---------------------------------------------------------------------------
__global__ __launch_bounds__(256) void k_zbt(const float* __restrict__ Z,
                                             bf16* __restrict__ Zb,
                                             bf16* __restrict__ ZbT) {
    __shared__ float t[64][65];
    int m0 = blockIdx.x * 64, j0 = blockIdx.y * 64, b = blockIdx.z;
    int c = threadIdx.x & 63, r0 = threadIdx.x >> 6;
#pragma unroll
    for (int s = 0; s < 16; s++) {
        int r = s * 4 + r0;
        int j = j0 + c;
        float v = (j < DP1) ? Z[((size_t)b * NP1 + m0 + r) * DP1 + j] : 0.f;
        t[r][c] = v;
        if (j < D_) Zb[((size_t)b * N_ + m0 + r) * D_ + j] = (bf16)v;
    }
    __syncthreads();
#pragma unroll
    for (int s = 0; s < 16; s++) {
        int rr = s * 4 + r0;
        int j = j0 + rr;
        if (j < DP1)
            ZbT[((size_t)b * DP1 + j) * MT + m0 + c] = (bf16)t[c][rr];
    }
}

// ---------------------------------------------------------------------------
// Fully fused layer kernel, 4-wave / 128-row blocks, 2 blocks per CU:
// round-5 verified counted-vmcnt raw-barrier pipeline + serpentine head
// passes (32 rows/wave inner loop unchanged), then fused post phase
// Z += (1/N) sum_h T_h.P_h^T on block-local T rows. LDS trimmed to ~71 KB
// (sl[4][16][40] via serialized-ns roundtrips) so two independent barrier
// domains co-reside per CU — block B computes while block A drains.
// Grid 512 = 256 CU x 2. bx==0 blocks run the n=1024 query-row tail.
// ---------------------------------------------------------------------------
__global__ __launch_bounds__(256, 2) void k_attn(const bf16* __restrict__ Zb,
                                                 const bf16* __restrict__ ZbT,
                                                 const bf16* __restrict__ Qt,
                                                 const bf16* __restrict__ Pb,
                                                 float* __restrict__ Z,
                                                 bf16* __restrict__ T,
                                                 bf16* __restrict__ Tlab,
                                                 int layer) {
    __shared__ bf16 zbS[2][32][256];   // XOR-swizzled: f(r) = r&7      (32 KB)
    __shared__ bf16 ztS[2][IPAD][32];  // f(r) = (r>>1)&3               (34 KB)
    __shared__ bf16 sl[4][16][40];     // per-wave roundtrip scratch    (5 KB)

    const int tid  = threadIdx.x;
    const int id   = blockIdx.x;
    const int wave = tid >> 6, lane = tid & 63;
    const int quad = lane >> 4, l16 = lane & 15;

    // XCD mapping: 64 blocks per XCD = 8 b x 8 n-blocks
    const int xcd = id & 7, u = id >> 3;
    const int b   = xcd + 8 * (u & 7);
    const int bx  = u >> 3;             // 0..7
    const int n0w = bx * 128 + wave * 32;

    const bf16* Zbb  = Zb  + (size_t)b * N_ * D_;
    const bf16* ZbTb = ZbT + (size_t)b * DP1 * MT;

    const int zrow  = wave * 2 + (lane >> 5);          // 0..7
    const int zscol = ((lane & 31) ^ (zrow & 7)) * 8;
    const int krow  = wave * 16 + (lane >> 2);         // 0..63
    const int kscol = ((lane & 3) ^ ((lane >> 3) & 3)) * 8;
    const int xs    = l16 & 7;
    const int kf    = (l16 >> 1) & 3;

    auto stage = [&](int mc_, int p_) {
        int m0 = mc_ * 32;
        const bf16* zsrc = Zbb + (size_t)(m0 + zrow) * D_ + zscol;
#pragma unroll
        for (int t = 0; t < 4; t++)
            async16(zsrc + (size_t)t * 8 * D_, &zbS[p_][t * 8 + wave * 2][0]);
        const bf16* ksrc = ZbTb + (size_t)krow * MT + m0 + kscol;
#pragma unroll
        for (int t = 0; t < 4; t++)
            async16(ksrc + (size_t)t * 64 * MT, &ztS[p_][t * 64 + wave * 16][0]);
        if (wave == 0)
            async16(ksrc + (size_t)256 * MT, &ztS[p_][256][0]);
    };

    int p = 0;   // current LDS buffer parity (tracked across heads for reuse)

    for (int h = 0; h < H_; h++) {
        const bf16* Qth = Qt + (size_t)(layer * H_ + h) * D_ * D_;

        if (h == 0) stage(0, 0);   // overlap first-chunk fill with ZQ phase

        f32x4 acc[2][17];
#pragma unroll
        for (int ns = 0; ns < 2; ns++)
#pragma unroll
            for (int it = 0; it < 17; it++) acc[ns][it] = (f32x4){0.f, 0.f, 0.f, 0.f};

        // ---- phase 1: ZQ^T -> zqa frags (b64-packed roundtrip, ns-serialized) ----
        bf16x8 zqa[2][8];
#pragma unroll 2
        for (int jc = 0; jc < 8; jc++) {
            f32x4 c00 = (f32x4){0.f,0.f,0.f,0.f}, c01 = c00, c10 = c00, c11 = c00;
#pragma unroll
            for (int kc = 0; kc < 8; kc++) {
                const bf16* qb = Qth + (size_t)(jc * 32 + l16) * D_ + kc * 32 + quad * 8;
                const bf16* az = Zbb + (size_t)(n0w + l16) * D_ + kc * 32 + quad * 8;
                bf16x8 q0 = *(const bf16x8*)(qb);
                bf16x8 q1 = *(const bf16x8*)(qb + 16 * D_);
                bf16x8 a0 = *(const bf16x8*)(az);
                bf16x8 a1 = *(const bf16x8*)(az + 16 * D_);
                c00 = mfma16(q0, a0, c00);
                c01 = mfma16(q0, a1, c01);
                c10 = mfma16(q1, a0, c10);
                c11 = mfma16(q1, a1, c11);
            }
            f32x4 cv[2][2] = {{c00, c01}, {c10, c11}};
            bf16x4 qsv[2];
#pragma unroll
            for (int jt = 0; jt < 2; jt++) {
                bf16x4 pk0, pk1;
#pragma unroll
                for (int r = 0; r < 4; r++) {
                    pk0[r] = (bf16)cv[jt][0][r];
                    pk1[r] = (bf16)cv[jt][1][r];
                }
                *(bf16x4*)(&sl[wave][l16][jt * 16 + quad * 4]) = pk0;
                qsv[jt] = pk1;
            }
            zqa[0][jc] = *(const bf16x8*)(&sl[wave][l16][quad * 8]);
#pragma unroll
            for (int jt = 0; jt < 2; jt++)
                *(bf16x4*)(&sl[wave][l16][jt * 16 + quad * 4]) = qsv[jt];
            zqa[1][jc] = *(const bf16x8*)(&sl[wave][l16][quad * 8]);
        }

        if (h == 0) {
            // chunk 0 must be resident before the pipeline starts
            asm volatile("s_waitcnt vmcnt(0)" ::: "memory");
            __builtin_amdgcn_s_barrier();
            __builtin_amdgcn_sched_barrier(0);
        }
        // h>0: current buffer p already holds this head's first chunk
        // (serpentine reuse: head h starts where head h-1 ended).

        for (int cc = 0; cc < NCHE; cc++) {
            const bool haveNext = (cc + 1 < NCHE);
            if (haveNext) {
                int mcn = (h & 1) ? (NCHE - 2 - cc) : (cc + 1);
                stage(mcn, p ^ 1);
                // wait own current-chunk loads; leave next-chunk (8/9) in flight
                if (wave == 0) asm volatile("s_waitcnt vmcnt(9)" ::: "memory");
                else           asm volatile("s_waitcnt vmcnt(8)" ::: "memory");
            } else {
                asm volatile("s_waitcnt vmcnt(0)" ::: "memory");
            }
            __builtin_amdgcn_s_barrier();        // all waves' chunk-cc loads landed
            __builtin_amdgcn_sched_barrier(0);

            // ---- S^T = relu(Zb_chunk . ZQ^T), ns-serialized roundtrip ----
            bf16x4 sv1[2];
#pragma unroll
            for (int mt = 0; mt < 2; mt++) {
                f32x4 st0 = (f32x4){0.f,0.f,0.f,0.f}, st1 = st0;
                const bf16* zr = &zbS[p][mt * 16 + l16][0];
                __builtin_amdgcn_s_setprio(1);
#pragma unroll
                for (int kc = 0; kc < 8; kc++) {
                    bf16x8 az = *(const bf16x8*)(zr + (((kc * 4 + quad) ^ xs) * 8));
                    st0 = mfma16(az, zqa[0][kc], st0);
                    st1 = mfma16(az, zqa[1][kc], st1);
                }
                __builtin_amdgcn_s_setprio(0);
                bf16x4 p0, p1;
#pragma unroll
                for (int r = 0; r < 4; r++) {
                    p0[r] = (bf16)(st0[r] > 0.f ? st0[r] : 0.f);
                    p1[r] = (bf16)(st1[r] > 0.f ? st1[r] : 0.f);
                }
                *(bf16x4*)(&sl[wave][l16][mt * 16 + quad * 4]) = p0;
                sv1[mt] = p1;
            }
            bf16x8 sfrag[2];
            sfrag[0] = *(const bf16x8*)(&sl[wave][l16][quad * 8]);
#pragma unroll
            for (int mt = 0; mt < 2; mt++)
                *(bf16x4*)(&sl[wave][l16][mt * 16 + quad * 4]) = sv1[mt];
            sfrag[1] = *(const bf16x8*)(&sl[wave][l16][quad * 8]);

            // ---- acc(T) += S . ZbT_chunk^T ----
            __builtin_amdgcn_s_setprio(1);
#pragma unroll
            for (int it = 0; it < 17; it++) {
                const bf16* kr = &ztS[p][it * 16 + l16][0];
                bf16x8 bk = *(const bf16x8*)(kr + ((quad ^ kf) * 8));
                acc[0][it] = mfma16(sfrag[0], bk, acc[0][it]);
                acc[1][it] = mfma16(sfrag[1], bk, acc[1][it]);
            }
            __builtin_amdgcn_s_setprio(0);

            __builtin_amdgcn_sched_barrier(0);
            __builtin_amdgcn_s_barrier();        // all waves done reading buf p
            if (haveNext) p ^= 1;
        }

        // ---- per-head epilogue: write T (bf16); j=256 goes to Tlab ----
        bf16* Th  = T    + (size_t)(b * H_ + h) * TR_ * D_;
        bf16* Tlh = Tlab + (size_t)(b * H_ + h) * TR_;
#pragma unroll
        for (int ns = 0; ns < 2; ns++)
#pragma unroll
            for (int it = 0; it < 17; it++)
#pragma unroll
                for (int r = 0; r < 4; r++) {
                    int n = n0w + ns * 16 + quad * 4 + r;   // < 1024
                    float v = acc[ns][it][r];
                    if (it < 16)
                        Th[(size_t)n * D_ + it * 16 + l16] = (bf16)v;
                    else if (l16 == 0)
                        Tlh[n] = (bf16)v;
                }
    }

    // ======== fused post phase: Z += (1/N) sum_h T_h . P_h^T ========
    __syncthreads();   // drain T/Tlab stores; sync Tlab across waves
    {
        f32x4 acc2[2][16];
#pragma unroll
        for (int ns = 0; ns < 2; ns++)
#pragma unroll
            for (int it = 0; it < 16; it++) acc2[ns][it] = (f32x4){0.f, 0.f, 0.f, 0.f};

        for (int h = 0; h < H_; h++) {
            const bf16* Th = T  + (size_t)(b * H_ + h) * TR_ * D_;
            const bf16* Ph = Pb + (size_t)(layer * H_ + h) * D_ * D_;
#pragma unroll 2
            for (int kc = 0; kc < 8; kc++) {
                bf16x8 af[2];
#pragma unroll
                for (int ns = 0; ns < 2; ns++) {
                    int row = n0w + ns * 16 + l16;   // block-local T rows
                    af[ns] = *(const bf16x8*)(Th + (size_t)row * D_ + kc * 32 + quad * 8);
                }
#pragma unroll
                for (int it = 0; it < 16; it++) {
                    bf16x8 bp = *(const bf16x8*)(Ph + (size_t)(it * 16 + l16) * D_ + kc * 32 + quad * 8);
                    acc2[0][it] = mfma16(af[0], bp, acc2[0][it]);
                    acc2[1][it] = mfma16(af[1], bp, acc2[1][it]);
                }
            }
        }

        const float inv = 1.0f / (float)N_;
#pragma unroll
        for (int ns = 0; ns < 2; ns++)
#pragma unroll
            for (int it = 0; it < 16; it++) {
                const int i = it * 16 + l16;                // < 256
                const int nbase = n0w + ns * 16 + quad * 4; // < 1024
#pragma unroll
                for (int r = 0; r < 4; r++) {
                    size_t zi = ((size_t)b * NP1 + nbase + r) * DP1 + i;
                    Z[zi] += acc2[ns][it][r] * inv;
                }
            }
        // label column i = 256 for this block's 128 rows
        if (tid < 128) {
            int n = bx * 128 + tid;
            float s = 0.f;
#pragma unroll
            for (int h = 0; h < H_; h++)
                s += (float)Tlab[(size_t)(b * H_ + h) * TR_ + n];
            Z[((size_t)b * NP1 + n) * DP1 + D_] += s * inv;
        }
    }

    // ---- n=1024 query row: bx==0 block of each b, all 4 heads fused ----
    if (bx == 0) {
        __syncthreads();   // all waves past post phase; zbS free for reuse
        float* lz1 = (float*)&zbS[0][0][0];   // 256 f32
        float* lzq = lz1 + 256;               // [4][256]
        float* lsS = lzq + 1024;              // [4][1024]
        float* lT  = lsS + 4096;              // [4][257]   (25.6 KB < zbS)
        lz1[tid] = Z[((size_t)b * NP1 + N_) * DP1 + tid];
        __syncthreads();
        for (int h2 = 0; h2 < H_; h2++) {   // zq[h][j=tid]
            const bf16* qr = Qt + ((size_t)(layer * H_ + h2) * D_ + tid) * D_;
            float a = 0.f;
            for (int i8 = 0; i8 < 32; i8++) {
                bf16x8 q = *(const bf16x8*)(qr + i8 * 8);
#pragma unroll
                for (int k = 0; k < 8; k++) a += lz1[i8 * 8 + k] * (float)q[k];
            }
            lzq[h2 * 256 + tid] = a;
        }
        __syncthreads();
        for (int m = tid; m < N_; m += 256) {   // one Zb sweep, 4 heads
            const bf16* zr = Zbb + (size_t)m * D_;
            float a0 = 0.f, a1 = 0.f, a2 = 0.f, a3 = 0.f;
            for (int j8 = 0; j8 < 32; j8++) {
                bf16x8 z8 = *(const bf16x8*)(zr + j8 * 8);
#pragma unroll
                for (int k = 0; k < 8; k++) {
                    float zv = (float)z8[k];
                    int j = j8 * 8 + k;
                    a0 += lzq[j] * zv;
                    a1 += lzq[256 + j] * zv;
                    a2 += lzq[512 + j] * zv;
                    a3 += lzq[768 + j] * zv;
                }
            }
            lsS[m]        = a0 > 0.f ? a0 : 0.f;
            lsS[1024 + m] = a1 > 0.f ? a1 : 0.f;
            lsS[2048 + m] = a2 > 0.f ? a2 : 0.f;
            lsS[3072 + m] = a3 > 0.f ? a3 : 0.f;
        }
        __syncthreads();
        for (int j = tid; j < DP1; j += 256) {   // one ZbT sweep, 4 heads
            const bf16* tr2 = ZbTb + (size_t)j * MT;
            float t0 = 0.f, t1 = 0.f, t2 = 0.f, t3 = 0.f;
            for (int m8 = 0; m8 < 128; m8++) {
                bf16x8 t8 = *(const bf16x8*)(tr2 + m8 * 8);
#pragma unroll
                for (int k = 0; k < 8; k++) {
                    float zv = (float)t8[k];
                    int m = m8 * 8 + k;
                    t0 += lsS[m] * zv;
                    t1 += lsS[1024 + m] * zv;
                    t2 += lsS[2048 + m] * zv;
                    t3 += lsS[3072 + m] * zv;
                }
            }
            lT[j] = t0; lT[257 + j] = t1; lT[514 + j] = t2; lT[771 + j] = t3;
        }
        __syncthreads();
        const float inv = 1.0f / (float)N_;
        {   // P contraction, all 4 heads, i = tid
            float out = 0.f;
            for (int h2 = 0; h2 < H_; h2++) {
                const bf16* pr = Pb + ((size_t)(layer * H_ + h2) * D_ + tid) * D_;
                for (int j8 = 0; j8 < 32; j8++) {
                    bf16x8 p8 = *(const bf16x8*)(pr + j8 * 8);
#pragma unroll
                    for (int k = 0; k < 8; k++)
                        out += lT[h2 * 257 + j8 * 8 + k] * (float)p8[k];
                }
            }
            Z[((size_t)b * NP1 + N_) * DP1 + tid] += out * inv;
        }
        if (tid == 0) {
            float lab = lT[256] + lT[513] + lT[770] + lT[1027];
            Z[((size_t)b * NP1 + N_) * DP1 + D_] += lab * inv;
        }
    }
}

// ---------------------------------------------------------------------------
extern "C" void kernel_launch(void* const* d_in, const int* in_sizes, int n_in,
                              void* d_out, int out_size, void* d_ws, size_t ws_size,
                              hipStream_t stream) {
    const float* Zin = (const float*)d_in[0];
    const float* ap  = (const float*)d_in[1];
    float* Z = (float*)d_out;

    char* ws = (char*)d_ws;
    const size_t sz_Zb  = (size_t)B_ * N_ * D_ * sizeof(bf16);          // 33.6 MB
    const size_t sz_ZbT = (size_t)B_ * DP1 * MT * sizeof(bf16);         // 33.7 MB
    const size_t sz_T   = (size_t)B_ * H_ * TR_ * D_ * sizeof(bf16);    // 134.2 MB
    const size_t sz_Tl  = (size_t)B_ * H_ * TR_ * sizeof(bf16);         // 0.5 MB
    const size_t sz_P   = (size_t)L_ * H_ * D_ * D_ * sizeof(bf16);     // 2 MB
    bf16* Zb  = (bf16*)ws;
    bf16* ZbT = (bf16*)(ws + sz_Zb);
    bf16* Tb  = (bf16*)(ws + sz_Zb + sz_ZbT);
    bf16* Tl  = (bf16*)(ws + sz_Zb + sz_ZbT + sz_T);
    bf16* Pb  = (bf16*)(ws + sz_Zb + sz_ZbT + sz_T + sz_Tl);
    bf16* Qt  = (bf16*)(ws + sz_Zb + sz_ZbT + sz_T + sz_Tl + sz_P);

    hipMemcpyAsync(Z, Zin, (size_t)B_ * NP1 * DP1 * sizeof(float),
                   hipMemcpyDeviceToDevice, stream);

    k_prep_pq<<<dim3((L_ * H_ * D_ * D_) / 256), 256, 0, stream>>>(ap, Pb, Qt);
    k_zbt<<<dim3(N_ / 64, 5, B_), 256, 0, stream>>>(Z, Zb, ZbT);   // layer 0

    for (int l = 0; l < L_; l++) {
        k_attn<<<dim3(512), 256, 0, stream>>>(Zb, ZbT, Qt, Pb, Z, Tb, Tl, l);
        if (l < L_ - 1)
            k_zbt<<<dim3(N_ / 64, 5, B_), 256, 0, stream>>>(Z, Zb, ZbT);
    }
}